// Round 14
// baseline (204.428 us; speedup 1.0000x reference)
//
#include <hip/hip_runtime.h>
#include <cmath>

#define TAPE_SZ 100000
#define N_SZ    50000
#define F_SZ    32
#define B_SZ    128
#define GSUB    32         // b's per group: row-segment = 32*2B = exactly one 64-B granule
#define NGRP    4          // groups; XCD x serves g = x&3 -> live slice 50000*64B = 3.2MB, L2-fit
#define HSPLIT  50000      // row half boundary (h0: row<HSPLIT, h1: row>=HSPLIT)
#define NBV     64         // n's per gather block
#define NCHUNK  ((N_SZ + NBV - 1) / NBV)   // 782
#define GRID_G  ((NCHUNK / 2) * 8)         // 3128: i&7 -> (g=i&3, sub=i>>2&1), chunk=(i>>3)*2+sub

// Manual round-to-nearest-even f32 -> bf16 bits.
static __device__ __forceinline__ unsigned short f32_to_bf16(float f) {
    unsigned int u = __float_as_uint(f);
    u = (u + 0x7fffu + ((u >> 16) & 1u)) >> 16;
    return (unsigned short)u;
}

// ---------------------------------------------------------------------------
// Transpose tape (B x TAPE fp32) -> tapeG[g][row][32b] bf16 (g = b/32).
// Each group's region is contiguous; the h-half of a group is a contiguous
// 3.2 MB (no L2 set-aliasing). Columns >= N_SZ write the fp32 tail into out.
// ---------------------------------------------------------------------------
__global__ __launch_bounds__(256) void transpose_g32(const float* __restrict__ in,
                                                     unsigned short* __restrict__ outG,
                                                     float* __restrict__ out) {
    __shared__ float tile[32][129];
    const int x0 = blockIdx.x * 32;
    const int tx = threadIdx.x;       // tape-col 0..31
    const int ty = threadIdx.y;       // 0..7

    #pragma unroll
    for (int yy = ty; yy < B_SZ; yy += 8)
        tile[tx][yy] = in[(size_t)yy * TAPE_SZ + x0 + tx];
    __syncthreads();

    const int tid = ty * 32 + tx;
    const int l = tid >> 3;           // row-in-tile 0..31
    const int o = tid & 7;            // 16-b chunk 0..7
    const int g = o >> 1;             // b-group 0..3
    const int hf = o & 1;             // half of group: b = g*32 + hf*16 ..+15
    unsigned short* dst = outG + ((size_t)g * TAPE_SZ + x0 + l) * GSUB + hf * 16;
    union { unsigned short u[8]; uint4 q; } p0, p1;
    #pragma unroll
    for (int k = 0; k < 8; ++k) {
        p0.u[k] = f32_to_bf16(tile[l][g * GSUB + hf * 16 + k]);
        p1.u[k] = f32_to_bf16(tile[l][g * GSUB + hf * 16 + 8 + k]);
    }
    *(uint4*)dst       = p0.q;
    *(uint4*)(dst + 8) = p1.q;

    // ---- fp32 tail: columns [N_SZ, TAPE_SZ) survive into out (per-column) ----
    if (x0 + tx >= N_SZ) {
        #pragma unroll
        for (int yy = ty; yy < B_SZ; yy += 8)
            out[(size_t)yy * TAPE_SZ + x0 + tx] = tile[tx][yy];
    }
}

// ---------------------------------------------------------------------------
// Gather-matmul, half HALF of the rows. Block = (chunk of 64 n, g).
// blockIdx&7 -> XCD; g = blockIdx&3 -> XCD x only touches group x&3, and this
// kernel only touches rows of half HALF -> live slice 3.2 MB, L2-RESIDENT BY
// CONSTRUCTION (stream boundary between h0/h1 = drift-proof global barrier).
// Thread = (n_local, seg): 4 lanes x 16 B = one 64-B granule per (n,f) ->
// 6.4M total requests (the floor). Uniform f-loop, batch-8 loads (MLP 8);
// out-of-half entries predicated (q=0 -> +0, exec-mask, no branches).
// HALF 0: writes f32 partials to acc[n][b]. HALF 1: combines + bias + act +
// coalesced epilogue stores.
// ---------------------------------------------------------------------------
template<int HALF>
__global__ __launch_bounds__(256) void gather_h(
    const unsigned short* __restrict__ tapeG,
    const float* __restrict__ weights,
    const float* __restrict__ bias,
    const int*   __restrict__ in_idx,
    const int*   __restrict__ out_idx,
    const int*   __restrict__ act_type,
    float* __restrict__ acc,
    float* __restrict__ out) {
    __shared__ union {
        int2  iw[NBV][33];     // (.x = row, .y = weight bits); pitch 33
        float x[GSUB][66];     // HALF==1 epilogue stage [b_local][n], aliased
    } u;
    __shared__ float s_bias[NBV];
    __shared__ int   s_act[NBV];
    __shared__ int   s_oidx[NBV];

    const int tid   = threadIdx.x;
    const int i     = blockIdx.x;
    const int g     = i & 3;              // b-group == XCD&3 under %8 round-robin
    const int sub   = (i >> 2) & 1;
    const int chunk = (i >> 3) * 2 + sub;
    const int n0    = chunk * NBV;
    const int nend  = min(NBV, N_SZ - n0);

    for (int t = tid; t < nend * 32; t += 256) {
        const int n = t >> 5, f = t & 31;
        u.iw[n][f] = make_int2(in_idx[(size_t)n0 * 32 + t],
                               __float_as_int(weights[(size_t)n0 * 32 + t]));
    }
    if (HALF == 1 && tid < nend) {
        s_bias[tid] = bias[n0 + tid];
        s_act[tid]  = act_type[n0 + tid];
        s_oidx[tid] = out_idx[n0 + tid];
    }
    __syncthreads();

    const int nl  = tid >> 2;             // n_local 0..63
    const int seg = tid & 3;              // granule segment: b_sub = 8*seg .. 8*seg+7
    const bool an = (nl < nend);
    const unsigned short* tg = tapeG + (size_t)g * TAPE_SZ * GSUB + seg * 8;

    float a[8];
    #pragma unroll
    for (int k = 0; k < 8; ++k) a[k] = 0.f;

    #pragma unroll
    for (int fo = 0; fo < 32; fo += 8) {
        int r8[8]; float w8[8];
        #pragma unroll
        for (int j = 0; j < 8; ++j) {
            const int2 iw = u.iw[nl][fo + j];
            r8[j] = iw.x; w8[j] = __int_as_float(iw.y);
        }
        uint4 q8[8];
        #pragma unroll
        for (int j = 0; j < 8; ++j) {
            q8[j] = make_uint4(0u, 0u, 0u, 0u);
            const bool c = an && (HALF == 0 ? (r8[j] < HSPLIT) : (r8[j] >= HSPLIT));
            if (c) q8[j] = *(const uint4*)(tg + (size_t)r8[j] * GSUB);
        }
        #pragma unroll
        for (int j = 0; j < 8; ++j) {
            const float wv = w8[j];
            a[0] = fmaf(__uint_as_float(q8[j].x << 16),         wv, a[0]);
            a[1] = fmaf(__uint_as_float(q8[j].x & 0xffff0000u), wv, a[1]);
            a[2] = fmaf(__uint_as_float(q8[j].y << 16),         wv, a[2]);
            a[3] = fmaf(__uint_as_float(q8[j].y & 0xffff0000u), wv, a[3]);
            a[4] = fmaf(__uint_as_float(q8[j].z << 16),         wv, a[4]);
            a[5] = fmaf(__uint_as_float(q8[j].z & 0xffff0000u), wv, a[5]);
            a[6] = fmaf(__uint_as_float(q8[j].w << 16),         wv, a[6]);
            a[7] = fmaf(__uint_as_float(q8[j].w & 0xffff0000u), wv, a[7]);
        }
    }

    float* ap = acc + (size_t)(n0 + nl) * B_SZ + g * GSUB + seg * 8;
    if (HALF == 0) {
        if (an) {
            *(float4*)(ap)     = make_float4(a[0], a[1], a[2], a[3]);
            *(float4*)(ap + 4) = make_float4(a[4], a[5], a[6], a[7]);
        }
        return;
    }

    // ---- HALF == 1: combine partials + bias + activation ----
    if (an) {
        const float4 p0 = *(const float4*)(ap);
        const float4 p1 = *(const float4*)(ap + 4);
        a[0] += p0.x; a[1] += p0.y; a[2] += p0.z; a[3] += p0.w;
        a[4] += p1.x; a[5] += p1.y; a[6] += p1.z; a[7] += p1.w;
        const float bz = s_bias[nl];
        const int   at = s_act[nl];
        #pragma unroll
        for (int k = 0; k < 8; ++k) {
            const float v = a[k] + bz;
            a[k] = (at == 0) ? fmaxf(v, 0.f) : tanhf(v);
        }
    }
    __syncthreads();   // all iw reads complete before aliased x writes
    if (an) {
        #pragma unroll
        for (int k = 0; k < 8; ++k) u.x[seg * 8 + k][nl] = a[k];
    }
    __syncthreads();

    // ---- epilogue: coalesced float4 row stores (consec out_idx fast path) ----
    const int quads = (nend + 3) >> 2;
    for (int it = tid; it < GSUB * quads; it += 256) {
        int bl, j4;
        if (nend == NBV) { bl = it >> 4; j4 = it & 15; }
        else             { bl = it / quads; j4 = it - bl * quads; }
        const int nq  = j4 * 4;
        const int oc0 = s_oidx[nq];
        float* orow = out + (size_t)(g * GSUB + bl) * TAPE_SZ;
        const bool consec = (nq + 3 < nend) &&
                            (s_oidx[nq + 1] == oc0 + 1) &&
                            (s_oidx[nq + 2] == oc0 + 2) &&
                            (s_oidx[nq + 3] == oc0 + 3) && ((oc0 & 3) == 0);
        if (consec) {
            *(float4*)(orow + oc0) = make_float4(u.x[bl][nq + 0], u.x[bl][nq + 1],
                                                 u.x[bl][nq + 2], u.x[bl][nq + 3]);
        } else {
            #pragma unroll
            for (int c = 0; c < 4; ++c)
                if (nq + c < nend) orow[s_oidx[nq + c]] = u.x[bl][nq + c];
        }
    }
}

// ---------------------------------------------------------------------------
// Fallback (workspace too small): direct uncoalesced gather. Correct, slow.
// ---------------------------------------------------------------------------
__global__ __launch_bounds__(128) void gather_fallback(const float* __restrict__ tape,
                                                       const float* __restrict__ weights,
                                                       const float* __restrict__ bias,
                                                       const int*   __restrict__ in_idx,
                                                       const int*   __restrict__ out_idx,
                                                       const int*   __restrict__ act_type,
                                                       float* __restrict__ out) {
    const int n = blockIdx.x;
    const int b = threadIdx.x;
    float acc = 0.f;
    for (int f = 0; f < F_SZ; ++f) {
        acc += tape[(size_t)b * TAPE_SZ + in_idx[(size_t)n * F_SZ + f]] *
               weights[(size_t)n * F_SZ + f];
    }
    acc += bias[n];
    acc = (act_type[n] == 0) ? fmaxf(acc, 0.f) : tanhf(acc);
    out[(size_t)b * TAPE_SZ + out_idx[n]] = acc;
}

__global__ __launch_bounds__(256) void copy_tail_fb(const float* __restrict__ tape,
                                                    float* __restrict__ out) {
    const int n4 = (TAPE_SZ - N_SZ) / 4;
    int i = blockIdx.x * blockDim.x + threadIdx.x;
    int b = blockIdx.y;
    if (i < n4) {
        const float4* src = (const float4*)(tape + (size_t)b * TAPE_SZ + N_SZ);
        float4*       dst = (float4*)(out  + (size_t)b * TAPE_SZ + N_SZ);
        dst[i] = src[i];
    }
}

extern "C" void kernel_launch(void* const* d_in, const int* in_sizes, int n_in,
                              void* d_out, int out_size, void* d_ws, size_t ws_size,
                              hipStream_t stream) {
    const float* tape    = (const float*)d_in[0];
    const float* weights = (const float*)d_in[1];
    const float* bias    = (const float*)d_in[2];
    const int*   in_idx  = (const int*)d_in[3];
    const int*   out_idx = (const int*)d_in[4];
    const int*   act     = (const int*)d_in[5];
    float*       out     = (float*)d_out;

    const size_t one = (size_t)TAPE_SZ * B_SZ * sizeof(unsigned short);   // 25.6 MB
    // need: tapeG (25.6 MB) + f32 acc (50000*128*4 = 25.6 MB) = 2*one (R2-proven available)
    if (ws_size >= 2 * one) {
        unsigned short* tapeG = (unsigned short*)d_ws;
        float*          accp  = (float*)((char*)d_ws + one);
        transpose_g32<<<dim3(TAPE_SZ / 32), dim3(32, 8), 0, stream>>>(tape, tapeG, out);
        gather_h<0><<<dim3(GRID_G), dim3(256), 0, stream>>>(
            tapeG, weights, bias, in_idx, out_idx, act, accp, out);
        gather_h<1><<<dim3(GRID_G), dim3(256), 0, stream>>>(
            tapeG, weights, bias, in_idx, out_idx, act, accp, out);
    } else {
        copy_tail_fb<<<dim3(((TAPE_SZ - N_SZ) / 4 + 255) / 256, B_SZ), 256, 0, stream>>>(tape, out);
        gather_fallback<<<dim3(N_SZ), 128, 0, stream>>>(
            tape, weights, bias, in_idx, out_idx, act, out);
    }
}

// Round 16
// 170.442 us; speedup vs baseline: 1.1994x; 1.1994x over previous
//
#include <hip/hip_runtime.h>
#include <cmath>

#define TAPE_SZ 100000
#define N_SZ    50000
#define F_SZ    32
#define B_SZ    128
#define NB      16      // n's per gather block (50000/16 = 3125 exact)
#define NGATHER 3125

// Manual round-to-nearest-even f32 -> bf16 bits.
static __device__ __forceinline__ unsigned short f32_to_bf16(float f) {
    unsigned int u = __float_as_uint(f);
    u = (u + 0x7fffu + ((u >> 16) & 1u)) >> 16;
    return (unsigned short)u;
}

// ---------------------------------------------------------------------------
// Kernel A: transpose tape (B x TAPE fp32) -> tapeT (TAPE x B bf16), 16B
// packed stores. R15: the fp32 tail (columns >= N_SZ) is fused here via the
// R8/R14-verified per-column guard -- the tile is already staged in LDS, so
// this saves the gather kernel's separate 25.6-MB tape re-read.
// ---------------------------------------------------------------------------
__global__ __launch_bounds__(256) void transpose_tape(const float* __restrict__ in,
                                                      unsigned short* __restrict__ outT,
                                                      float* __restrict__ out) {
    __shared__ float tile[32][129];
    const int x0 = blockIdx.x * 32;
    const int tx = threadIdx.x;       // x_local 0..31
    const int ty = threadIdx.y;       // 0..7

    #pragma unroll
    for (int yy = ty; yy < B_SZ; yy += 8)
        tile[tx][yy] = in[(size_t)yy * TAPE_SZ + x0 + tx];
    __syncthreads();

    const int tid = ty * 32 + tx;
    const int oct = tid & 15;         // b-octet (8 bf16 = 16B)
    const int xl0 = tid >> 4;         // 0..15
    #pragma unroll
    for (int xx = xl0; xx < 32; xx += 16) {
        const float* src = &tile[xx][oct * 8];
        union { unsigned short u[8]; uint4 q; } pk;
        #pragma unroll
        for (int k = 0; k < 8; ++k)
            pk.u[k] = f32_to_bf16(src[k]);
        *(uint4*)(outT + (size_t)(x0 + xx) * B_SZ + oct * 8) = pk.q;
    }

    // ---- fp32 tail: columns [N_SZ, TAPE_SZ) survive into out (per-column) ----
    if (x0 + tx >= N_SZ) {
        #pragma unroll
        for (int yy = ty; yy < B_SZ; yy += 8)
            out[(size_t)yy * TAPE_SZ + x0 + tx] = tile[tx][yy];
    }
}

// ---------------------------------------------------------------------------
// Kernel B: gather-matmul -- the session-start R6-proven core, restored.
// Full 256-B rows: 16 lanes x uint4 consume one whole tape row per (n,f)
// -> 6.4M 64-B granule-probes (the floor; all 32-B-segment redesigns issued
// 12.8M and landed 83-89 us). Batch-8 loads (MLP 8). Tail blocks removed
// (tail fused into transpose).
// ---------------------------------------------------------------------------
__global__ __launch_bounds__(256) void gather_mm(const unsigned short* __restrict__ tapeT,
                                                 const float* __restrict__ weights,
                                                 const float* __restrict__ bias,
                                                 const int*   __restrict__ in_idx,
                                                 const int*   __restrict__ out_idx,
                                                 const int*   __restrict__ act_type,
                                                 float* __restrict__ out) {
    __shared__ int   s_idx[NB][33];   // pitch 33: conflict-free broadcast reads
    __shared__ float s_w[NB][33];
    __shared__ float s_bias[NB];
    __shared__ int   s_act[NB];
    __shared__ int   s_oidx[NB];
    __shared__ float s_x[NB][132];    // [n_local][b]

    const int tid = threadIdx.x;
    const int n0 = blockIdx.x * NB;

    #pragma unroll
    for (int t = tid; t < NB * 32; t += 256) {
        const int n = t >> 5, f = t & 31;
        s_idx[n][f] = in_idx[(size_t)n0 * 32 + t];
        s_w[n][f]   = weights[(size_t)n0 * 32 + t];
    }
    if (tid < NB) {
        s_bias[tid] = bias[n0 + tid];
        s_act[tid]  = act_type[n0 + tid];
        s_oidx[tid] = out_idx[n0 + tid];
    }
    __syncthreads();

    const int nl = tid >> 4;              // n_local 0..15
    const int bx = tid & 15;              // b-octet: b = 8*bx .. 8*bx+7
    float a0 = 0.f, a1 = 0.f, a2 = 0.f, a3 = 0.f, a4 = 0.f, a5 = 0.f, a6 = 0.f, a7 = 0.f;

    #pragma unroll
    for (int fo = 0; fo < 32; fo += 8) {
        int   i8[8]; float w8[8];
        #pragma unroll
        for (int j = 0; j < 8; ++j) { i8[j] = s_idx[nl][fo + j]; w8[j] = s_w[nl][fo + j]; }
        uint4 q8[8];
        #pragma unroll
        for (int j = 0; j < 8; ++j)
            q8[j] = *(const uint4*)(tapeT + (size_t)i8[j] * B_SZ + bx * 8);
        #pragma unroll
        for (int j = 0; j < 8; ++j) {
            const float w = w8[j];
            a0 = fmaf(__uint_as_float(q8[j].x << 16),         w, a0);
            a1 = fmaf(__uint_as_float(q8[j].x & 0xffff0000u), w, a1);
            a2 = fmaf(__uint_as_float(q8[j].y << 16),         w, a2);
            a3 = fmaf(__uint_as_float(q8[j].y & 0xffff0000u), w, a3);
            a4 = fmaf(__uint_as_float(q8[j].z << 16),         w, a4);
            a5 = fmaf(__uint_as_float(q8[j].z & 0xffff0000u), w, a5);
            a6 = fmaf(__uint_as_float(q8[j].w << 16),         w, a6);
            a7 = fmaf(__uint_as_float(q8[j].w & 0xffff0000u), w, a7);
        }
    }

    const float bz = s_bias[nl];
    a0 += bz; a1 += bz; a2 += bz; a3 += bz; a4 += bz; a5 += bz; a6 += bz; a7 += bz;
    if (s_act[nl] == 0) {
        a0 = fmaxf(a0, 0.f); a1 = fmaxf(a1, 0.f); a2 = fmaxf(a2, 0.f); a3 = fmaxf(a3, 0.f);
        a4 = fmaxf(a4, 0.f); a5 = fmaxf(a5, 0.f); a6 = fmaxf(a6, 0.f); a7 = fmaxf(a7, 0.f);
    } else {
        a0 = tanhf(a0); a1 = tanhf(a1); a2 = tanhf(a2); a3 = tanhf(a3);
        a4 = tanhf(a4); a5 = tanhf(a5); a6 = tanhf(a6); a7 = tanhf(a7);
    }
    {
        const int b8 = bx * 8;
        s_x[nl][b8 + 0] = a0; s_x[nl][b8 + 1] = a1; s_x[nl][b8 + 2] = a2; s_x[nl][b8 + 3] = a3;
        s_x[nl][b8 + 4] = a4; s_x[nl][b8 + 5] = a5; s_x[nl][b8 + 6] = a6; s_x[nl][b8 + 7] = a7;
    }
    __syncthreads();

    // Epilogue: wave w owns n-quad g=w; lanes sweep b. float4 store over 4
    // consecutive output columns when possible; scalar fallback otherwise.
    const int g  = tid >> 6;              // n-quad 0..3
    const int b0 = tid & 63;              // b
    const int oc0 = s_oidx[g * 4];
    const bool consec = (s_oidx[g * 4 + 1] == oc0 + 1) &&
                        (s_oidx[g * 4 + 2] == oc0 + 2) &&
                        (s_oidx[g * 4 + 3] == oc0 + 3) && ((oc0 & 3) == 0);
    #pragma unroll
    for (int rep = 0; rep < 2; ++rep) {
        const int b = b0 + rep * 64;
        const float4 v = make_float4(s_x[g * 4 + 0][b], s_x[g * 4 + 1][b],
                                     s_x[g * 4 + 2][b], s_x[g * 4 + 3][b]);
        if (consec) {
            *(float4*)(out + (size_t)b * TAPE_SZ + oc0) = v;
        } else {
            out[(size_t)b * TAPE_SZ + s_oidx[g * 4 + 0]] = v.x;
            out[(size_t)b * TAPE_SZ + s_oidx[g * 4 + 1]] = v.y;
            out[(size_t)b * TAPE_SZ + s_oidx[g * 4 + 2]] = v.z;
            out[(size_t)b * TAPE_SZ + s_oidx[g * 4 + 3]] = v.w;
        }
    }
}

// ---------------------------------------------------------------------------
// Fallback (workspace too small): direct uncoalesced gather. Correct, slow.
// ---------------------------------------------------------------------------
__global__ __launch_bounds__(128) void gather_fallback(const float* __restrict__ tape,
                                                       const float* __restrict__ weights,
                                                       const float* __restrict__ bias,
                                                       const int*   __restrict__ in_idx,
                                                       const int*   __restrict__ out_idx,
                                                       const int*   __restrict__ act_type,
                                                       float* __restrict__ out) {
    const int n = blockIdx.x;
    const int b = threadIdx.x;
    float acc = 0.f;
    for (int f = 0; f < F_SZ; ++f) {
        acc += tape[(size_t)b * TAPE_SZ + in_idx[(size_t)n * F_SZ + f]] *
               weights[(size_t)n * F_SZ + f];
    }
    acc += bias[n];
    acc = (act_type[n] == 0) ? fmaxf(acc, 0.f) : tanhf(acc);
    out[(size_t)b * TAPE_SZ + out_idx[n]] = acc;
}

__global__ __launch_bounds__(256) void copy_tail_fb(const float* __restrict__ tape,
                                                    float* __restrict__ out) {
    const int n4 = (TAPE_SZ - N_SZ) / 4;
    int i = blockIdx.x * blockDim.x + threadIdx.x;
    int b = blockIdx.y;
    if (i < n4) {
        const float4* src = (const float4*)(tape + (size_t)b * TAPE_SZ + N_SZ);
        float4*       dst = (float4*)(out  + (size_t)b * TAPE_SZ + N_SZ);
        dst[i] = src[i];
    }
}

extern "C" void kernel_launch(void* const* d_in, const int* in_sizes, int n_in,
                              void* d_out, int out_size, void* d_ws, size_t ws_size,
                              hipStream_t stream) {
    const float* tape    = (const float*)d_in[0];
    const float* weights = (const float*)d_in[1];
    const float* bias    = (const float*)d_in[2];
    const int*   in_idx  = (const int*)d_in[3];
    const int*   out_idx = (const int*)d_in[4];
    const int*   act     = (const int*)d_in[5];
    float*       out     = (float*)d_out;

    const size_t need = (size_t)TAPE_SZ * B_SZ * sizeof(unsigned short);
    if (ws_size >= need) {
        unsigned short* tapeT = (unsigned short*)d_ws;
        transpose_tape<<<dim3(TAPE_SZ / 32), dim3(32, 8), 0, stream>>>(tape, tapeT, out);
        gather_mm<<<dim3(NGATHER), dim3(256), 0, stream>>>(
            tapeT, weights, bias, in_idx, out_idx, act, out);
    } else {
        copy_tail_fb<<<dim3(((TAPE_SZ - N_SZ) / 4 + 255) / 256, B_SZ), 256, 0, stream>>>(tape, out);
        gather_fallback<<<dim3(N_SZ), 128, 0, stream>>>(
            tape, weights, bias, in_idx, out_idx, act, out);
    }
}